// Round 20
// baseline (88.086 us; speedup 1.0000x reference)
//
#include <hip/hip_runtime.h>
#include <hip/hip_bf16.h>

#define NSEQ 4096
#define NBH 32
#define LOG32 3.4657359028f
#define QSCALE 0.125f

typedef unsigned short us8 __attribute__((ext_vector_type(8)));
typedef __bf16 bf16x8 __attribute__((ext_vector_type(8)));
typedef float f32x4 __attribute__((ext_vector_type(4)));
typedef unsigned int u32x4 __attribute__((ext_vector_type(4)));

__device__ __forceinline__ unsigned short f2b(float x) {
    __bf16 h = (__bf16)x;                       // native RNE cvt on gfx950
    return __builtin_bit_cast(unsigned short, h);
}
__device__ __forceinline__ unsigned pk2(float lo, float hi) {
    return (unsigned)f2b(lo) | ((unsigned)f2b(hi) << 16);
}
__device__ __forceinline__ bf16x8 cvt8(float4 a, float4 b) {
    us8 u;
    u[0] = f2b(a.x); u[1] = f2b(a.y); u[2] = f2b(a.z); u[3] = f2b(a.w);
    u[4] = f2b(b.x); u[5] = f2b(b.y); u[6] = f2b(b.z); u[7] = f2b(b.w);
    return __builtin_bit_cast(bf16x8, u);
}
// nontemporal 16B load: builtin requires a NATIVE vector pointer (ext_vector_type),
// not HIP_vector_type float4 — load as f32x4 and bit_cast back (same dwordx4 nt instr).
__device__ __forceinline__ float4 ntl4(const float4* p) {
    f32x4 v = __builtin_nontemporal_load((const f32x4*)p);
    return __builtin_bit_cast(float4, v);
}

// ---------------- kernel 1: LSH hash — R3/R14-measured 512-block version, verbatim ----------------
// FINAL. Do not regrid (1024 blocks: +12.3us, R12); do not restructure loads/stores
// (+16us, R15). Loads stay cacheable: qkv must remain L3-resident for attn's gathers.
__global__ __launch_bounds__(256) void hash_kernel(const float* __restrict__ qkv,
                                                   const float* __restrict__ proj,
                                                   unsigned short* __restrict__ hsh) {
    __shared__ float pdT[512];            // transposed proj: pdT[r*64+d]
    int tid = threadIdx.x;
    for (int j = tid; j < 512; j += 256) pdT[j] = proj[(j & 63) * 8 + (j >> 6)];
    __syncthreads();
    int j0 = blockIdx.x * 256 + tid;
    #pragma unroll
    for (int rep = 0; rep < 2; ++rep) {
        int j = j0 + rep * 131072;
        int ch = rep;                      // 0=q, 1=k
        int bh = (j >> 12) & 31;
        int i = j & 4095;
        int b = bh >> 4, h = bh & 15;
        const float4* src = (const float4*)(qkv + ((size_t)((b * NSEQ + i) * 3 + ch)) * 1024 + h * 64);
        double acc[8] = {0, 0, 0, 0, 0, 0, 0, 0};
        for (int d4 = 0; d4 < 16; ++d4) {
            float4 x = src[d4];
            double xx = x.x, xy = x.y, xz = x.z, xw = x.w;
            #pragma unroll
            for (int r = 0; r < 8; ++r) {
                const float4 p = *(const float4*)&pdT[r * 64 + d4 * 4];
                acc[r] += xx * p.x + xy * p.y + xz * p.z + xw * p.w;
            }
        }
        int c = 0;
        #pragma unroll
        for (int r = 0; r < 8; ++r)
            if (acc[r] > 0.0) c |= (1 << r);
        hsh[j] = (unsigned short)(c ^ (c >> 1));
    }
}

// ---------------- kernel 2: ballot-ranked stable sort + sampled-idx side table ----------------
__global__ __launch_bounds__(1024) void sort_kernel(const unsigned short* __restrict__ hsh,
                                                    int* __restrict__ qidx,
                                                    int* __restrict__ kidx,
                                                    int* __restrict__ skidx,
                                                    const int* __restrict__ sampled) {
    int blk = blockIdx.x;
    int pass = blk >> 5, bh = blk & 31;
    const unsigned short* src = hsh + pass * 131072 + bh * 4096;
    int* outg = (pass ? kidx : qidx) + bh * 4096;
    int tid = threadIdx.x;
    int wv = tid >> 6, ln = tid & 63;
    __shared__ int hist[64][256];          // 64 KB
    __shared__ unsigned char rnk[4096];
    __shared__ unsigned char bkt[4096];
    __shared__ unsigned short posmap[4096];   // 8 KB: pos -> row
    __shared__ int base[256];
    for (int jj = tid; jj < 64 * 256; jj += 1024) (&hist[0][0])[jj] = 0;
    __syncthreads();
    // each wave ranks 4 segments of 64 elements
    for (int s = wv; s < 64; s += 16) {
        int i = s * 64 + ln;
        int q = src[i];
        bkt[i] = (unsigned char)q;
        unsigned long long mask = ~0ULL;
        #pragma unroll
        for (int bit = 0; bit < 8; ++bit) {
            unsigned long long bb = __ballot((q >> bit) & 1);
            mask &= ((q >> bit) & 1) ? bb : ~bb;
        }
        int r = __popcll(mask & ((1ULL << ln) - 1ULL));
        rnk[i] = (unsigned char)r;
        if (r == 0) hist[s][q] = __popcll(mask);
    }
    __syncthreads();
    // per-bucket prefix over segments + bucket totals
    int cnt_tot = 0;
    if (tid < 256) {
        int tot = 0;
        #pragma unroll 8
        for (int s = 0; s < 64; ++s) { int c = hist[s][tid]; hist[s][tid] = tot; tot += c; }
        base[tid] = tot;
        cnt_tot = tot;
    }
    __syncthreads();
    // Hillis-Steele inclusive scan over 256 bucket totals
    for (int off = 1; off < 256; off <<= 1) {
        int t = (tid >= off && tid < 256) ? base[tid - off] : 0;
        __syncthreads();
        if (tid >= off && tid < 256) base[tid] += t;
        __syncthreads();
    }
    int incl = 0;
    if (tid < 256) incl = base[tid];
    __syncthreads();
    if (tid < 256) base[tid] = incl - cnt_tot;   // exclusive global base
    __syncthreads();
    // fully parallel stable scatter (+ posmap)
    for (int i = tid; i < 4096; i += 1024) {
        int q = bkt[i];
        int pos = base[q] + hist[i >> 6][q] + rnk[i];
        outg[pos] = i;
        posmap[pos] = (unsigned short)i;
    }
    if (pass == 1) {
        __syncthreads();
        if (tid < 128)
            skidx[bh * 128 + tid] = posmap[sampled[bh * 128 + tid]];
    }
}

// ---------------- kernel 3: fused attention — R18 structure + nt loads on read-once paths ----------------
// Q rows, block-K rows (r0), block-V rows (vkey<128, wave-uniform split) are read
// exactly once -> nontemporal (no L2 allocate). Sampled K/V (32x reuse per bh) and
// idx tables stay cacheable. Same addresses/values; only the nt flag changes.
__global__ __launch_bounds__(512, 4) void attn_kernel(const float* __restrict__ qkv,
                                                      const int* __restrict__ sampled,
                                                      const int* __restrict__ qidx_g,
                                                      const int* __restrict__ kidx_g,
                                                      const int* __restrict__ skidx,
                                                      float* __restrict__ out) {
    int bid = blockIdx.x;
    int gb = (bid & 7) * 128 + (bid >> 3);   // XCD swizzle: sampled-set L2 reuse (+0.75us, R11)
    int bh = gb >> 5, g = gb & 31;
    int b = bh >> 4, h = bh & 15;
    int tid = threadIdx.x;
    int w = tid >> 6, l = tid & 63;
    int l15 = l & 15, lq = l >> 4;

    __shared__ us8 KP[2048];                 // 32 KB: K rows x 8 chunks, swz=(r^(r>>2))&7
    __shared__ us8 VT[2048];                 // 32 KB: V^T [dim][32 chunks], swz=d&7
    __shared__ float colbias[256];

    const int* qbase_g = qidx_g + bh * NSEQ + g * 128;
    const int* kbase_g = kidx_g + bh * NSEQ + g * 128;
    const int* smp = sampled + bh * 128;
    const int* skp = skidx + bh * 128;

    // ---- colbias into LDS (no barrier here; K-ready barrier covers it) ----
    if (tid < 128) {
        colbias[tid] = 0.0f;
    } else if (tid < 256) {
        int sp = smp[tid - 128];
        colbias[tid] = ((sp >> 7) == g) ? -1e30f : LOG32;
    }

    // ---- Q: direct idx then gather (read-once -> nt) ----
    int qr = qbase_g[w * 16 + l15];
    const float4* qbase = (const float4*)(qkv + ((size_t)((b * NSEQ + qr) * 3 + 0)) * 1024 + h * 64 + lq * 8);
    float4 qa0 = ntl4(qbase);
    float4 qa1 = ntl4(qbase + 1);
    float4 qb0 = ntl4(qbase + 8);
    float4 qb1 = ntl4(qbase + 9);

    // ---- K staging: r0 block keys (read-once -> nt) + r1 sampled keys (reused -> cached) ----
    {
        int r0 = tid >> 2, qt = tid & 3;
        int r1 = r0 + 128;
        int kr0 = kbase_g[r0];
        int kr1 = skp[r0];
        const float4* src0 = (const float4*)(qkv + ((size_t)((b * NSEQ + kr0) * 3 + 1)) * 1024 + h * 64 + qt * 16);
        const float4* src1 = (const float4*)(qkv + ((size_t)((b * NSEQ + kr1) * 3 + 1)) * 1024 + h * 64 + qt * 16);
        float4 k0 = ntl4(src0 + 0);
        float4 k1 = ntl4(src0 + 1);
        float4 k2 = ntl4(src0 + 2);
        float4 k3 = ntl4(src0 + 3);
        float4 k4 = src1[0], k5 = src1[1], k6 = src1[2], k7 = src1[3];
        int sw0 = (r0 ^ (r0 >> 2)) & 7;
        int sw1 = (r1 ^ (r1 >> 2)) & 7;
        KP[r0 * 8 + ((qt * 2) ^ sw0)]     = __builtin_bit_cast(us8, cvt8(k0, k1));
        KP[r0 * 8 + ((qt * 2 + 1) ^ sw0)] = __builtin_bit_cast(us8, cvt8(k2, k3));
        KP[r1 * 8 + ((qt * 2) ^ sw1)]     = __builtin_bit_cast(us8, cvt8(k4, k5));
        KP[r1 * 8 + ((qt * 2 + 1) ^ sw1)] = __builtin_bit_cast(us8, cvt8(k6, k7));
    }
    // ---- V staging (2 threads/key): block half nt (read-once), sampled half cached ----
    // vkey<128 <=> tid<256 <=> waves 0-3: the branch is wave-uniform.
    {
        int vkey = tid >> 1, vhalf = tid & 1;
        unsigned short* vt_us = (unsigned short*)VT;
        int kc8 = vkey >> 3, ke = vkey & 7;
        if (vkey < 128) {
            int vr = kbase_g[vkey];
            const float4* src = (const float4*)(qkv + ((size_t)((b * NSEQ + vr) * 3 + 2)) * 1024 + h * 64 + vhalf * 32);
            #pragma unroll
            for (int d4 = 0; d4 < 8; ++d4) {
                float4 f = ntl4(src + d4);
                int d = vhalf * 32 + d4 * 4;
                vt_us[(((d + 0) * 32 + (kc8 ^ ((d + 0) & 7))) << 3) + ke] = f2b(f.x);
                vt_us[(((d + 1) * 32 + (kc8 ^ ((d + 1) & 7))) << 3) + ke] = f2b(f.y);
                vt_us[(((d + 2) * 32 + (kc8 ^ ((d + 2) & 7))) << 3) + ke] = f2b(f.z);
                vt_us[(((d + 3) * 32 + (kc8 ^ ((d + 3) & 7))) << 3) + ke] = f2b(f.w);
            }
        } else {
            int vr = skp[vkey - 128];
            const float4* src = (const float4*)(qkv + ((size_t)((b * NSEQ + vr) * 3 + 2)) * 1024 + h * 64 + vhalf * 32);
            #pragma unroll
            for (int d4 = 0; d4 < 8; ++d4) {
                float4 f = src[d4];
                int d = vhalf * 32 + d4 * 4;
                vt_us[(((d + 0) * 32 + (kc8 ^ ((d + 0) & 7))) << 3) + ke] = f2b(f.x);
                vt_us[(((d + 1) * 32 + (kc8 ^ ((d + 1) & 7))) << 3) + ke] = f2b(f.y);
                vt_us[(((d + 2) * 32 + (kc8 ^ ((d + 2) & 7))) << 3) + ke] = f2b(f.z);
                vt_us[(((d + 3) * 32 + (kc8 ^ ((d + 3) & 7))) << 3) + ke] = f2b(f.w);
            }
        }
    }
    __syncthreads();

    // ---- phase 1: swapped QK^T with permuted key tiling ----
    // sA[s][j] = S[q=w*16+l15][key=32s+8lq+j], sB[s][j] = key 32s+8lq+4+j
    bf16x8 q0 = cvt8(qa0, qa1);
    bf16x8 q1 = cvt8(qb0, qb1);
    f32x4 sA[8], sB[8];
    int ra = 8 * (l15 >> 2) + (l15 & 3);   // a-frag row -> key offset within 32-key group
    #pragma unroll
    for (int s = 0; s < 8; ++s) {
        int krA = s * 32 + ra;
        int krB = krA + 4;
        int swA = (krA ^ (krA >> 2)) & 7;
        int swB = (krB ^ (krB >> 2)) & 7;
        bf16x8 kA0 = __builtin_bit_cast(bf16x8, KP[krA * 8 + (lq ^ swA)]);
        bf16x8 kA1 = __builtin_bit_cast(bf16x8, KP[krA * 8 + ((lq + 4) ^ swA)]);
        bf16x8 kB0 = __builtin_bit_cast(bf16x8, KP[krB * 8 + (lq ^ swB)]);
        bf16x8 kB1 = __builtin_bit_cast(bf16x8, KP[krB * 8 + ((lq + 4) ^ swB)]);
        f32x4 accA = {0.f, 0.f, 0.f, 0.f}, accB = {0.f, 0.f, 0.f, 0.f};
        accA = __builtin_amdgcn_mfma_f32_16x16x32_bf16(kA0, q0, accA, 0, 0, 0);
        accA = __builtin_amdgcn_mfma_f32_16x16x32_bf16(kA1, q1, accA, 0, 0, 0);
        accB = __builtin_amdgcn_mfma_f32_16x16x32_bf16(kB0, q0, accB, 0, 0, 0);
        accB = __builtin_amdgcn_mfma_f32_16x16x32_bf16(kB1, q1, accB, 0, 0, 0);
        float4 cbA = *(const float4*)&colbias[s * 32 + lq * 8];
        float4 cbB = *(const float4*)&colbias[s * 32 + lq * 8 + 4];
        sA[s][0] = accA[0] * QSCALE + cbA.x;
        sA[s][1] = accA[1] * QSCALE + cbA.y;
        sA[s][2] = accA[2] * QSCALE + cbA.z;
        sA[s][3] = accA[3] * QSCALE + cbA.w;
        sB[s][0] = accB[0] * QSCALE + cbB.x;
        sB[s][1] = accB[1] * QSCALE + cbB.y;
        sB[s][2] = accB[2] * QSCALE + cbB.z;
        sB[s][3] = accB[3] * QSCALE + cbB.w;
    }

    // ---- phase 2: softmax — lane owns q=l15; partners at xor 16/32 ----
    float m = -1e30f;
    #pragma unroll
    for (int s = 0; s < 8; ++s)
        #pragma unroll
        for (int j = 0; j < 4; ++j) {
            m = fmaxf(m, sA[s][j]);
            m = fmaxf(m, sB[s][j]);
        }
    m = fmaxf(m, __shfl_xor(m, 16));
    m = fmaxf(m, __shfl_xor(m, 32));
    float sum = 0.f;
    #pragma unroll
    for (int s = 0; s < 8; ++s)
        #pragma unroll
        for (int j = 0; j < 4; ++j) {
            float pa = __expf(sA[s][j] - m); sA[s][j] = pa; sum += pa;
            float pb = __expf(sB[s][j] - m); sB[s][j] = pb; sum += pb;
        }
    sum += __shfl_xor(sum, 16);
    sum += __shfl_xor(sum, 32);
    float rs = 1.0f / sum;

    // ---- epilogue row indices: one int4 per lane (hidden under PV) ----
    int4 qr4 = *(const int4*)&qbase_g[w * 16 + lq * 4];

    // ---- phase 3: PV straight from registers (P pre-normalized) ----
    f32x4 oacc[4] = {{0.f,0.f,0.f,0.f},{0.f,0.f,0.f,0.f},{0.f,0.f,0.f,0.f},{0.f,0.f,0.f,0.f}};
    #pragma unroll
    for (int s = 0; s < 8; ++s) {
        u32x4 pw;
        pw[0] = pk2(sA[s][0] * rs, sA[s][1] * rs);
        pw[1] = pk2(sA[s][2] * rs, sA[s][3] * rs);
        pw[2] = pk2(sB[s][0] * rs, sB[s][1] * rs);
        pw[3] = pk2(sB[s][2] * rs, sB[s][3] * rs);
        bf16x8 pa = __builtin_bit_cast(bf16x8, pw);
        #pragma unroll
        for (int ct = 0; ct < 4; ++ct) {
            int d = ct * 16 + l15;
            bf16x8 vb = __builtin_bit_cast(bf16x8, VT[d * 32 + ((s * 4 + lq) ^ (d & 7))]);
            oacc[ct] = __builtin_amdgcn_mfma_f32_16x16x32_bf16(pa, vb, oacc[ct], 0, 0, 0);
        }
    }

    // ---- epilogue: scatter to original query positions (non-temporal: write-once) ----
    int qrows[4] = {qr4.x, qr4.y, qr4.z, qr4.w};
    #pragma unroll
    for (int j = 0; j < 4; ++j) {
        size_t obase = ((size_t)((b * NSEQ + qrows[j]) * 16 + h)) * 64;
        #pragma unroll
        for (int ct = 0; ct < 4; ++ct)
            __builtin_nontemporal_store(oacc[ct][j], &out[obase + ct * 16 + l15]);
    }
}

extern "C" void kernel_launch(void* const* d_in, const int* in_sizes, int n_in,
                              void* d_out, int out_size, void* d_ws, size_t ws_size,
                              hipStream_t stream) {
    const float* qkv = (const float*)d_in[0];      // [2,4096,3,16,64] f32
    const float* proj = (const float*)d_in[1];     // [64,8] f32
    const int* sampled = (const int*)d_in[2];      // [2,16,128] i32
    float* outp = (float*)d_out;                   // [2,4096,16,64] f32

    int* qidx = (int*)d_ws;                        // 32*4096 ints
    int* kidx = qidx + NBH * NSEQ;                 // 32*4096 ints
    unsigned short* hsh = (unsigned short*)(kidx + NBH * NSEQ); // 2*32*4096 ushort
    int* skidx = (int*)(hsh + 2 * NBH * NSEQ);     // 32*128 ints

    hash_kernel<<<512, 256, 0, stream>>>(qkv, proj, hsh);
    sort_kernel<<<64, 1024, 0, stream>>>(hsh, qidx, kidx, skidx, sampled);
    attn_kernel<<<NBH * 32, 512, 0, stream>>>(qkv, sampled, qidx, kidx, skidx, outp);
}

// Round 21
// 65.510 us; speedup vs baseline: 1.3446x; 1.3446x over previous
//
#include <hip/hip_runtime.h>
#include <hip/hip_bf16.h>

#define NSEQ 4096
#define NBH 32
#define LOG32 3.4657359028f
#define QSCALE 0.125f

typedef unsigned short us8 __attribute__((ext_vector_type(8)));
typedef __bf16 bf16x8 __attribute__((ext_vector_type(8)));
typedef float f32x4 __attribute__((ext_vector_type(4)));
typedef unsigned int u32x4 __attribute__((ext_vector_type(4)));

__device__ __forceinline__ unsigned short f2b(float x) {
    __bf16 h = (__bf16)x;                       // native RNE cvt on gfx950
    return __builtin_bit_cast(unsigned short, h);
}
__device__ __forceinline__ unsigned pk2(float lo, float hi) {
    return (unsigned)f2b(lo) | ((unsigned)f2b(hi) << 16);
}
__device__ __forceinline__ bf16x8 cvt8(float4 a, float4 b) {
    us8 u;
    u[0] = f2b(a.x); u[1] = f2b(a.y); u[2] = f2b(a.z); u[3] = f2b(a.w);
    u[4] = f2b(b.x); u[5] = f2b(b.y); u[6] = f2b(b.z); u[7] = f2b(b.w);
    return __builtin_bit_cast(bf16x8, u);
}

// ---------------- kernel 1: LSH hash — R3/R14-measured 512-block version, verbatim ----------------
// FINAL. Do not regrid (1024 blocks: +12.3us, R12); do not restructure loads/stores
// (+16us, R15). Loads stay CACHEABLE — qkv is L3-resident and L2-warm for attn;
// nt loads cost +21.7us (R20).
__global__ __launch_bounds__(256) void hash_kernel(const float* __restrict__ qkv,
                                                   const float* __restrict__ proj,
                                                   unsigned short* __restrict__ hsh) {
    __shared__ float pdT[512];            // transposed proj: pdT[r*64+d]
    int tid = threadIdx.x;
    for (int j = tid; j < 512; j += 256) pdT[j] = proj[(j & 63) * 8 + (j >> 6)];
    __syncthreads();
    int j0 = blockIdx.x * 256 + tid;
    #pragma unroll
    for (int rep = 0; rep < 2; ++rep) {
        int j = j0 + rep * 131072;
        int ch = rep;                      // 0=q, 1=k
        int bh = (j >> 12) & 31;
        int i = j & 4095;
        int b = bh >> 4, h = bh & 15;
        const float4* src = (const float4*)(qkv + ((size_t)((b * NSEQ + i) * 3 + ch)) * 1024 + h * 64);
        double acc[8] = {0, 0, 0, 0, 0, 0, 0, 0};
        for (int d4 = 0; d4 < 16; ++d4) {
            float4 x = src[d4];
            double xx = x.x, xy = x.y, xz = x.z, xw = x.w;
            #pragma unroll
            for (int r = 0; r < 8; ++r) {
                const float4 p = *(const float4*)&pdT[r * 64 + d4 * 4];
                acc[r] += xx * p.x + xy * p.y + xz * p.z + xw * p.w;
            }
        }
        int c = 0;
        #pragma unroll
        for (int r = 0; r < 8; ++r)
            if (acc[r] > 0.0) c |= (1 << r);
        hsh[j] = (unsigned short)(c ^ (c >> 1));
    }
}

// ---------------- kernel 2: ballot-ranked stable sort + sampled-idx side table ----------------
__global__ __launch_bounds__(1024) void sort_kernel(const unsigned short* __restrict__ hsh,
                                                    int* __restrict__ qidx,
                                                    int* __restrict__ kidx,
                                                    int* __restrict__ skidx,
                                                    const int* __restrict__ sampled) {
    int blk = blockIdx.x;
    int pass = blk >> 5, bh = blk & 31;
    const unsigned short* src = hsh + pass * 131072 + bh * 4096;
    int* outg = (pass ? kidx : qidx) + bh * 4096;
    int tid = threadIdx.x;
    int wv = tid >> 6, ln = tid & 63;
    __shared__ int hist[64][256];          // 64 KB
    __shared__ unsigned char rnk[4096];
    __shared__ unsigned char bkt[4096];
    __shared__ unsigned short posmap[4096];   // 8 KB: pos -> row
    __shared__ int base[256];
    for (int jj = tid; jj < 64 * 256; jj += 1024) (&hist[0][0])[jj] = 0;
    __syncthreads();
    // each wave ranks 4 segments of 64 elements
    for (int s = wv; s < 64; s += 16) {
        int i = s * 64 + ln;
        int q = src[i];
        bkt[i] = (unsigned char)q;
        unsigned long long mask = ~0ULL;
        #pragma unroll
        for (int bit = 0; bit < 8; ++bit) {
            unsigned long long bb = __ballot((q >> bit) & 1);
            mask &= ((q >> bit) & 1) ? bb : ~bb;
        }
        int r = __popcll(mask & ((1ULL << ln) - 1ULL));
        rnk[i] = (unsigned char)r;
        if (r == 0) hist[s][q] = __popcll(mask);
    }
    __syncthreads();
    // per-bucket prefix over segments + bucket totals
    int cnt_tot = 0;
    if (tid < 256) {
        int tot = 0;
        #pragma unroll 8
        for (int s = 0; s < 64; ++s) { int c = hist[s][tid]; hist[s][tid] = tot; tot += c; }
        base[tid] = tot;
        cnt_tot = tot;
    }
    __syncthreads();
    // Hillis-Steele inclusive scan over 256 bucket totals
    for (int off = 1; off < 256; off <<= 1) {
        int t = (tid >= off && tid < 256) ? base[tid - off] : 0;
        __syncthreads();
        if (tid >= off && tid < 256) base[tid] += t;
        __syncthreads();
    }
    int incl = 0;
    if (tid < 256) incl = base[tid];
    __syncthreads();
    if (tid < 256) base[tid] = incl - cnt_tot;   // exclusive global base
    __syncthreads();
    // fully parallel stable scatter (+ posmap)
    for (int i = tid; i < 4096; i += 1024) {
        int q = bkt[i];
        int pos = base[q] + hist[i >> 6][q] + rnk[i];
        outg[pos] = i;
        posmap[pos] = (unsigned short)i;
    }
    if (pass == 1) {
        __syncthreads();
        if (tid < 128)
            skidx[bh * 128 + tid] = posmap[sampled[bh * 128 + tid]];
    }
}

// ---------------- kernel 3: fused attention — R18-measured best (nt stores only) ----------------
// Cacheable gathers (nt loads: +21.7us, R20). NT stores: -2.1us (R18). skidx: -1us (R16).
// XCD swizzle: -0.75us (R11). Swapped-QK^T + in-register P + permuted key tiling (R8).
__global__ __launch_bounds__(512, 4) void attn_kernel(const float* __restrict__ qkv,
                                                      const int* __restrict__ sampled,
                                                      const int* __restrict__ qidx_g,
                                                      const int* __restrict__ kidx_g,
                                                      const int* __restrict__ skidx,
                                                      float* __restrict__ out) {
    int bid = blockIdx.x;
    int gb = (bid & 7) * 128 + (bid >> 3);   // XCD swizzle: sampled-set L2 reuse
    int bh = gb >> 5, g = gb & 31;
    int b = bh >> 4, h = bh & 15;
    int tid = threadIdx.x;
    int w = tid >> 6, l = tid & 63;
    int l15 = l & 15, lq = l >> 4;

    __shared__ us8 KP[2048];                 // 32 KB: K rows x 8 chunks, swz=(r^(r>>2))&7
    __shared__ us8 VT[2048];                 // 32 KB: V^T [dim][32 chunks], swz=d&7
    __shared__ float colbias[256];

    const int* qbase_g = qidx_g + bh * NSEQ + g * 128;
    const int* kbase_g = kidx_g + bh * NSEQ + g * 128;
    const int* smp = sampled + bh * 128;
    const int* skp = skidx + bh * 128;

    // ---- colbias into LDS (no barrier here; K-ready barrier covers it) ----
    if (tid < 128) {
        colbias[tid] = 0.0f;
    } else if (tid < 256) {
        int sp = smp[tid - 128];
        colbias[tid] = ((sp >> 7) == g) ? -1e30f : LOG32;
    }

    // ---- Q: direct idx then gather (this wave's 16 rows) ----
    int qr = qbase_g[w * 16 + l15];
    const float* qbase = qkv + ((size_t)((b * NSEQ + qr) * 3 + 0)) * 1024 + h * 64 + lq * 8;
    float4 qa0 = *(const float4*)(qbase);
    float4 qa1 = *(const float4*)(qbase + 4);
    float4 qb0 = *(const float4*)(qbase + 32);
    float4 qb1 = *(const float4*)(qbase + 36);

    // ---- K staging: row r0 (block keys) + r1 (sampled keys via skidx, 1-level) ----
    {
        int r0 = tid >> 2, qt = tid & 3;
        int r1 = r0 + 128;
        int kr0 = kbase_g[r0];
        int kr1 = skp[r0];
        const float4* src0 = (const float4*)(qkv + ((size_t)((b * NSEQ + kr0) * 3 + 1)) * 1024 + h * 64 + qt * 16);
        const float4* src1 = (const float4*)(qkv + ((size_t)((b * NSEQ + kr1) * 3 + 1)) * 1024 + h * 64 + qt * 16);
        float4 k0 = src0[0], k1 = src0[1], k2 = src0[2], k3 = src0[3];
        float4 k4 = src1[0], k5 = src1[1], k6 = src1[2], k7 = src1[3];
        int sw0 = (r0 ^ (r0 >> 2)) & 7;
        int sw1 = (r1 ^ (r1 >> 2)) & 7;
        KP[r0 * 8 + ((qt * 2) ^ sw0)]     = __builtin_bit_cast(us8, cvt8(k0, k1));
        KP[r0 * 8 + ((qt * 2 + 1) ^ sw0)] = __builtin_bit_cast(us8, cvt8(k2, k3));
        KP[r1 * 8 + ((qt * 2) ^ sw1)]     = __builtin_bit_cast(us8, cvt8(k4, k5));
        KP[r1 * 8 + ((qt * 2 + 1) ^ sw1)] = __builtin_bit_cast(us8, cvt8(k6, k7));
    }
    // ---- V staging (256 keys; 2 threads/key, 32 dims each), swz by d&7 ----
    {
        int vkey = tid >> 1, vhalf = tid & 1;
        int vr = (vkey < 128) ? kbase_g[vkey] : skp[vkey - 128];
        const float4* src = (const float4*)(qkv + ((size_t)((b * NSEQ + vr) * 3 + 2)) * 1024 + h * 64 + vhalf * 32);
        unsigned short* vt_us = (unsigned short*)VT;
        int kc8 = vkey >> 3, ke = vkey & 7;
        #pragma unroll
        for (int d4 = 0; d4 < 8; ++d4) {
            float4 f = src[d4];
            int d = vhalf * 32 + d4 * 4;
            vt_us[(((d + 0) * 32 + (kc8 ^ ((d + 0) & 7))) << 3) + ke] = f2b(f.x);
            vt_us[(((d + 1) * 32 + (kc8 ^ ((d + 1) & 7))) << 3) + ke] = f2b(f.y);
            vt_us[(((d + 2) * 32 + (kc8 ^ ((d + 2) & 7))) << 3) + ke] = f2b(f.z);
            vt_us[(((d + 3) * 32 + (kc8 ^ ((d + 3) & 7))) << 3) + ke] = f2b(f.w);
        }
    }
    __syncthreads();

    // ---- phase 1: swapped QK^T with permuted key tiling ----
    // sA[s][j] = S[q=w*16+l15][key=32s+8lq+j], sB[s][j] = key 32s+8lq+4+j
    bf16x8 q0 = cvt8(qa0, qa1);
    bf16x8 q1 = cvt8(qb0, qb1);
    f32x4 sA[8], sB[8];
    int ra = 8 * (l15 >> 2) + (l15 & 3);   // a-frag row -> key offset within 32-key group
    #pragma unroll
    for (int s = 0; s < 8; ++s) {
        int krA = s * 32 + ra;
        int krB = krA + 4;
        int swA = (krA ^ (krA >> 2)) & 7;
        int swB = (krB ^ (krB >> 2)) & 7;
        bf16x8 kA0 = __builtin_bit_cast(bf16x8, KP[krA * 8 + (lq ^ swA)]);
        bf16x8 kA1 = __builtin_bit_cast(bf16x8, KP[krA * 8 + ((lq + 4) ^ swA)]);
        bf16x8 kB0 = __builtin_bit_cast(bf16x8, KP[krB * 8 + (lq ^ swB)]);
        bf16x8 kB1 = __builtin_bit_cast(bf16x8, KP[krB * 8 + ((lq + 4) ^ swB)]);
        f32x4 accA = {0.f, 0.f, 0.f, 0.f}, accB = {0.f, 0.f, 0.f, 0.f};
        accA = __builtin_amdgcn_mfma_f32_16x16x32_bf16(kA0, q0, accA, 0, 0, 0);
        accA = __builtin_amdgcn_mfma_f32_16x16x32_bf16(kA1, q1, accA, 0, 0, 0);
        accB = __builtin_amdgcn_mfma_f32_16x16x32_bf16(kB0, q0, accB, 0, 0, 0);
        accB = __builtin_amdgcn_mfma_f32_16x16x32_bf16(kB1, q1, accB, 0, 0, 0);
        float4 cbA = *(const float4*)&colbias[s * 32 + lq * 8];
        float4 cbB = *(const float4*)&colbias[s * 32 + lq * 8 + 4];
        sA[s][0] = accA[0] * QSCALE + cbA.x;
        sA[s][1] = accA[1] * QSCALE + cbA.y;
        sA[s][2] = accA[2] * QSCALE + cbA.z;
        sA[s][3] = accA[3] * QSCALE + cbA.w;
        sB[s][0] = accB[0] * QSCALE + cbB.x;
        sB[s][1] = accB[1] * QSCALE + cbB.y;
        sB[s][2] = accB[2] * QSCALE + cbB.z;
        sB[s][3] = accB[3] * QSCALE + cbB.w;
    }

    // ---- phase 2: softmax — lane owns q=l15; partners at xor 16/32 ----
    float m = -1e30f;
    #pragma unroll
    for (int s = 0; s < 8; ++s)
        #pragma unroll
        for (int j = 0; j < 4; ++j) {
            m = fmaxf(m, sA[s][j]);
            m = fmaxf(m, sB[s][j]);
        }
    m = fmaxf(m, __shfl_xor(m, 16));
    m = fmaxf(m, __shfl_xor(m, 32));
    float sum = 0.f;
    #pragma unroll
    for (int s = 0; s < 8; ++s)
        #pragma unroll
        for (int j = 0; j < 4; ++j) {
            float pa = __expf(sA[s][j] - m); sA[s][j] = pa; sum += pa;
            float pb = __expf(sB[s][j] - m); sB[s][j] = pb; sum += pb;
        }
    sum += __shfl_xor(sum, 16);
    sum += __shfl_xor(sum, 32);
    float rs = 1.0f / sum;

    // ---- epilogue row indices: one int4 per lane (hidden under PV) ----
    int4 qr4 = *(const int4*)&qbase_g[w * 16 + lq * 4];

    // ---- phase 3: PV straight from registers (P pre-normalized) ----
    f32x4 oacc[4] = {{0.f,0.f,0.f,0.f},{0.f,0.f,0.f,0.f},{0.f,0.f,0.f,0.f},{0.f,0.f,0.f,0.f}};
    #pragma unroll
    for (int s = 0; s < 8; ++s) {
        u32x4 pw;
        pw[0] = pk2(sA[s][0] * rs, sA[s][1] * rs);
        pw[1] = pk2(sA[s][2] * rs, sA[s][3] * rs);
        pw[2] = pk2(sB[s][0] * rs, sB[s][1] * rs);
        pw[3] = pk2(sB[s][2] * rs, sB[s][3] * rs);
        bf16x8 pa = __builtin_bit_cast(bf16x8, pw);
        #pragma unroll
        for (int ct = 0; ct < 4; ++ct) {
            int d = ct * 16 + l15;
            bf16x8 vb = __builtin_bit_cast(bf16x8, VT[d * 32 + ((s * 4 + lq) ^ (d & 7))]);
            oacc[ct] = __builtin_amdgcn_mfma_f32_16x16x32_bf16(pa, vb, oacc[ct], 0, 0, 0);
        }
    }

    // ---- epilogue: scatter to original query positions (non-temporal: write-once) ----
    int qrows[4] = {qr4.x, qr4.y, qr4.z, qr4.w};
    #pragma unroll
    for (int j = 0; j < 4; ++j) {
        size_t obase = ((size_t)((b * NSEQ + qrows[j]) * 16 + h)) * 64;
        #pragma unroll
        for (int ct = 0; ct < 4; ++ct)
            __builtin_nontemporal_store(oacc[ct][j], &out[obase + ct * 16 + l15]);
    }
}

extern "C" void kernel_launch(void* const* d_in, const int* in_sizes, int n_in,
                              void* d_out, int out_size, void* d_ws, size_t ws_size,
                              hipStream_t stream) {
    const float* qkv = (const float*)d_in[0];      // [2,4096,3,16,64] f32
    const float* proj = (const float*)d_in[1];     // [64,8] f32
    const int* sampled = (const int*)d_in[2];      // [2,16,128] i32
    float* outp = (float*)d_out;                   // [2,4096,16,64] f32

    int* qidx = (int*)d_ws;                        // 32*4096 ints
    int* kidx = qidx + NBH * NSEQ;                 // 32*4096 ints
    unsigned short* hsh = (unsigned short*)(kidx + NBH * NSEQ); // 2*32*4096 ushort
    int* skidx = (int*)(hsh + 2 * NBH * NSEQ);     // 32*128 ints

    hash_kernel<<<512, 256, 0, stream>>>(qkv, proj, hsh);
    sort_kernel<<<64, 1024, 0, stream>>>(hsh, qidx, kidx, skidx, sampled);
    attn_kernel<<<NBH * 32, 512, 0, stream>>>(qkv, sampled, qidx, kidx, skidx, outp);
}